// Round 1
// baseline (566.903 us; speedup 1.0000x reference)
//
#include <hip/hip_runtime.h>
#include <math.h>

#define IN_DIM 16
#define HDIM   128
#define HEADS  4
#define HH     512   // HEADS*HDIM
#define FFH    256   // 2*HDIM
#define NEG_SLOPE 0.2f

typedef _Float16 half8 __attribute__((ext_vector_type(8)));
typedef _Float16 h8 __attribute__((ext_vector_type(8)));
typedef _Float16 h4 __attribute__((ext_vector_type(4)));
typedef _Float16 h2 __attribute__((ext_vector_type(2)));
typedef float f32x4 __attribute__((ext_vector_type(4)));

struct __align__(8) Edge { int src; _Float16 ea0, ea1; };

static __device__ inline float hsum8(h8 v) {
    h4 a = __builtin_shufflevector(v, v, 0, 1, 2, 3) +
           __builtin_shufflevector(v, v, 4, 5, 6, 7);
    h2 b = __builtin_shufflevector(a, a, 0, 1) +
           __builtin_shufflevector(a, a, 2, 3);
    return (float)b[0] + (float)b[1];
}

// ---------------------------------------------------------------------------
// x pad: xh[n][64] = f16(x[n][16]) zero-padded
// ---------------------------------------------------------------------------
__global__ void xpad_kernel(const float* __restrict__ x, _Float16* __restrict__ xh, int n) {
    int idx = blockIdx.x * 256 + threadIdx.x;
    if (idx >= n * 64) return;
    int r = idx >> 6, k = idx & 63;
    xh[idx] = (k < IN_DIM) ? (_Float16)x[r * IN_DIM + k] : (_Float16)0.0f;
}

// ---------------------------------------------------------------------------
// Weight convert+transpose+K-pad: W[Ksrc][N] fp32 -> WT[N][Kd] f16 (zero pad)
// ---------------------------------------------------------------------------
struct WDesc { const float* src; _Float16* dst; int Ksrc; int lgKd; int lgN; };
struct WDescs { WDesc d[15]; };
__global__ void wconv_kernel(WDescs ds) {
    WDesc w = ds.d[blockIdx.y];
    int Kd = 1 << w.lgKd;
    int total = 1 << (w.lgKd + w.lgN);
    for (int idx = blockIdx.x * 256 + threadIdx.x; idx < total; idx += gridDim.x * 256) {
        int n2 = idx >> w.lgKd, k = idx & (Kd - 1);
        w.dst[idx] = (k < w.Ksrc) ? (_Float16)w.src[(k << w.lgN) + n2] : (_Float16)0.0f;
    }
}

// ---------------------------------------------------------------------------
// Flat f32 -> f16 convert for GAT attention weights / biases.
// we: lin_edge [3*1024], att: [3*512], cb: conv_bias01 [2*512]
// ---------------------------------------------------------------------------
__global__ void wcvt_kernel(const float* __restrict__ we, const float* __restrict__ att,
                            const float* __restrict__ cb,
                            _Float16* __restrict__ weh, _Float16* __restrict__ atth,
                            _Float16* __restrict__ cbh) {
    int i = blockIdx.x * 256 + threadIdx.x;
    if (i < 3072) weh[i] = (_Float16)we[i];
    else if (i < 4608) atth[i - 3072] = (_Float16)att[i - 3072];
    else if (i < 5632) cbh[i - 4608] = (_Float16)cb[i - 4608];
}

// ---------------------------------------------------------------------------
// Preprocess: degree + edge_attr sums (self-loop fill_value='mean')
// ---------------------------------------------------------------------------
__global__ void deg_kernel(const int* __restrict__ ei, const float* __restrict__ eattr,
                           float* deg, float* asum, int E) {
    int e = blockIdx.x * blockDim.x + threadIdx.x;
    if (e >= E) return;
    int d = ei[E + e];
    atomicAdd(&deg[d], 1.0f);
    atomicAdd(&asum[2 * d], eattr[2 * e]);
    atomicAdd(&asum[2 * d + 1], eattr[2 * e + 1]);
}

__global__ void scan_kernel(const float* __restrict__ deg, int* row_ptr, int* cur, int n) {
    __shared__ int sums[1024];
    int tid = threadIdx.x;
    int per = (n + 1023) / 1024;
    int s0 = tid * per;
    int s1 = s0 + per; if (s1 > n) s1 = n;
    int s = 0;
    for (int i = s0; i < s1; i++) s += (int)deg[i] + 1;
    int mysum = s;
    sums[tid] = s;
    __syncthreads();
    for (int dd = 1; dd < 1024; dd <<= 1) {
        int t = (tid >= dd) ? sums[tid - dd] : 0;
        __syncthreads();
        sums[tid] += t;
        __syncthreads();
    }
    int run = sums[tid] - mysum;   // exclusive prefix
    for (int i = s0; i < s1; i++) {
        row_ptr[i] = run; cur[i] = run;
        run += (int)deg[i] + 1;
    }
    if (tid == 1023) row_ptr[n] = sums[1023];
}

__global__ void scatter_kernel(const int* __restrict__ ei, const float* __restrict__ eattr,
                               const float* __restrict__ deg, const float* __restrict__ asum,
                               int* cur, Edge* csr, int E, int n) {
    int i = blockIdx.x * blockDim.x + threadIdx.x;
    if (i >= E + n) return;
    Edge ed;
    int pos;
    if (i < E) {
        int d = ei[E + i];
        pos = atomicAdd(&cur[d], 1);
        ed.src = ei[i];
        ed.ea0 = (_Float16)eattr[2 * i];
        ed.ea1 = (_Float16)eattr[2 * i + 1];
    } else {
        int nd = i - E;
        float dv = fmaxf(deg[nd], 1.0f);
        pos = atomicAdd(&cur[nd], 1);
        ed.src = nd;
        ed.ea0 = (_Float16)(asum[2 * nd] / dv);
        ed.ea1 = (_Float16)(asum[2 * nd + 1] / dv);
    }
    csr[pos] = ed;
}

// ---------------------------------------------------------------------------
// B-stationary MFMA GEMM for K<=128 (see r9 notes): BT staged once, B-frags
// in registers, barrier-free grid-stride M loop, A direct from global.
// ---------------------------------------------------------------------------
template <int KT, int OUTMODE>
__global__ __launch_bounds__(256) void gemm_bstat(const _Float16* __restrict__ A, int lda,
                                                  const _Float16* __restrict__ BT,
                                                  const float* __restrict__ bias,
                                                  float* __restrict__ C32,
                                                  _Float16* __restrict__ C16,
                                                  int M, int Nstride, int numMT) {
    const int PAD = 8, KC = KT / 32;
    __shared__ _Float16 Bs[128][KT + PAD];
    int tid = threadIdx.x;
    int wave = tid >> 6, lane = tid & 63;
    int quad = lane >> 4, l16 = lane & 15;
    int wrow = (wave >> 1) * 32, wcol = (wave & 1) * 64;
    int n0 = blockIdx.x * 128;

#pragma unroll
    for (int t = 0; t < KT / 16; t++) {
        int idx = tid + t * 256;
        int r = idx / (KT / 8), kb = (idx % (KT / 8)) * 8;
        *(half8*)&Bs[r][kb] = *(const half8*)(BT + (size_t)(n0 + r) * KT + kb);
    }
    __syncthreads();

    half8 bfrag[4][KC];
#pragma unroll
    for (int j = 0; j < 4; j++)
#pragma unroll
        for (int kc = 0; kc < KC; kc++)
            bfrag[j][kc] = *(const half8*)&Bs[wcol + j * 16 + l16][kc * 32 + quad * 8];

    float biasj[4];
#pragma unroll
    for (int j = 0; j < 4; j++)
        biasj[j] = bias ? bias[n0 + wcol + j * 16 + l16] : 0.0f;

    for (int mt = blockIdx.y; mt < numMT; mt += gridDim.y) {
        int rbase = mt * 64 + wrow;
        half8 af[2][KC];
#pragma unroll
        for (int i = 0; i < 2; i++) {
            int row = rbase + i * 16 + l16;
#pragma unroll
            for (int kc = 0; kc < KC; kc++)
                af[i][kc] = (row < M) ? *(const half8*)(A + (size_t)row * lda + kc * 32 + quad * 8)
                                      : (half8)(_Float16)0.0f;
        }
        f32x4 acc[2][4] = {};
#pragma unroll
        for (int kc = 0; kc < KC; kc++)
#pragma unroll
            for (int i = 0; i < 2; i++)
#pragma unroll
                for (int j = 0; j < 4; j++)
                    acc[i][j] = __builtin_amdgcn_mfma_f32_16x16x32_f16(af[i][kc], bfrag[j][kc], acc[i][j], 0, 0, 0);
#pragma unroll
        for (int i = 0; i < 2; i++) {
#pragma unroll
            for (int r = 0; r < 4; r++) {
                int row = rbase + i * 16 + quad * 4 + r;
                if (row >= M) continue;
#pragma unroll
                for (int j = 0; j < 4; j++) {
                    int col = n0 + wcol + j * 16 + l16;
                    float v = acc[i][j][r] + biasj[j];
                    if (OUTMODE == 2)
                        C32[(size_t)row * Nstride + col] = v;
                    C16[(size_t)row * Nstride + col] = (_Float16)v;
                }
            }
        }
    }
}

// ---------------------------------------------------------------------------
// Fused GEMM(+bias) + residual + LayerNorm for N=128, register-resident LN.
// ---------------------------------------------------------------------------
__global__ __launch_bounds__(256) void gemm_ln(const _Float16* __restrict__ A, int lda,
                                               const _Float16* __restrict__ BT,
                                               const float* __restrict__ bias,
                                               const float* __restrict__ R,
                                               const float* __restrict__ g,
                                               const float* __restrict__ b,
                                               float* __restrict__ C32,
                                               _Float16* __restrict__ C16,
                                               int M, int K) {
    const int BK = 64, PAD = 8;
    __shared__ _Float16 As[64][BK + PAD];
    __shared__ _Float16 Bs[128][BK + PAD];
    int tid = threadIdx.x;
    int wave = tid >> 6, lane = tid & 63;
    int quad = lane >> 4, l16 = lane & 15;
    int mBase = blockIdx.x * 64;

    f32x4 acc[8] = {};

    for (int k0 = 0; k0 < K; k0 += BK) {
#pragma unroll
        for (int t = 0; t < 2; t++) {
            int idx = tid + t * 256;
            int r = idx >> 3, kb = (idx & 7) * 8;
            half8 hv = {};
            int grow = mBase + r;
            if (grow < M) hv = *(const half8*)(A + (size_t)grow * lda + k0 + kb);
            *(half8*)&As[r][kb] = hv;
        }
#pragma unroll
        for (int t = 0; t < 4; t++) {
            int idx = tid + t * 256;
            int r = idx >> 3, kb = (idx & 7) * 8;
            *(half8*)&Bs[r][kb] = *(const half8*)(BT + (size_t)r * K + k0 + kb);
        }
        __syncthreads();
#pragma unroll
        for (int kc = 0; kc < 2; kc++) {
            half8 a = *(const half8*)&As[wave * 16 + l16][kc * 32 + quad * 8];
#pragma unroll
            for (int j = 0; j < 8; j++) {
                half8 bb = *(const half8*)&Bs[j * 16 + l16][kc * 32 + quad * 8];
                acc[j] = __builtin_amdgcn_mfma_f32_16x16x32_f16(a, bb, acc[j], 0, 0, 0);
            }
        }
        __syncthreads();
    }

    float gj[8], bj[8], biasj[8];
#pragma unroll
    for (int j = 0; j < 8; j++) {
        int col = j * 16 + l16;
        biasj[j] = bias[col];
        gj[j] = g[col];
        bj[j] = b[col];
    }
    int row0 = mBase + wave * 16 + quad * 4;
    float sum[4] = {}, sq[4] = {};
#pragma unroll
    for (int r = 0; r < 4; r++) {
        int row = row0 + r;
        bool ok = row < M;
        size_t base = (size_t)row * HDIM;
#pragma unroll
        for (int j = 0; j < 8; j++) {
            float v = acc[j][r] + biasj[j] + (ok ? R[base + j * 16 + l16] : 0.0f);
            acc[j][r] = v;
            sum[r] += v;
            sq[r] += v * v;
        }
    }
#pragma unroll
    for (int r = 0; r < 4; r++) {
#pragma unroll
        for (int off = 1; off < 16; off <<= 1) {
            sum[r] += __shfl_xor(sum[r], off);
            sq[r] += __shfl_xor(sq[r], off);
        }
    }
#pragma unroll
    for (int r = 0; r < 4; r++) {
        int row = row0 + r;
        if (row >= M) continue;
        size_t base = (size_t)row * HDIM;
        float mu = sum[r] * (1.0f / HDIM);
        float var = sq[r] * (1.0f / HDIM) - mu * mu;
        float invstd = rsqrtf(var + 1e-5f);
#pragma unroll
        for (int j = 0; j < 8; j++) {
            float o = (acc[j][r] - mu) * invstd * gj[j] + bj[j];
            C32[base + j * 16 + l16] = o;
            if (C16) C16[base + j * 16 + l16] = (_Float16)o;
        }
    }
}

// ---------------------------------------------------------------------------
// Fused FFN: C = LN(GELU(A@W1T + b1)@W2T + b2 + R) * g + b.
// ---------------------------------------------------------------------------
__global__ __launch_bounds__(256) void ffn_fused(const _Float16* __restrict__ A,
                                                 const _Float16* __restrict__ W1T,
                                                 const float* __restrict__ b1,
                                                 const _Float16* __restrict__ W2T,
                                                 const float* __restrict__ b2,
                                                 const float* __restrict__ R,
                                                 const float* __restrict__ g,
                                                 const float* __restrict__ b,
                                                 float* __restrict__ C32,
                                                 _Float16* __restrict__ C16,
                                                 int M) {
    __shared__ _Float16 Ws[128][128 + 8];
    __shared__ _Float16 Mid[64][256 + 8];
    int tid = threadIdx.x;
    int wave = tid >> 6, lane = tid & 63;
    int quad = lane >> 4, l16 = lane & 15;
    int mBase = blockIdx.x * 64;

    half8 afrag[4];
    {
        int row = mBase + wave * 16 + l16;
#pragma unroll
        for (int kc = 0; kc < 4; kc++) {
            if (row < M)
                afrag[kc] = *(const half8*)(A + (size_t)row * HDIM + kc * 32 + quad * 8);
            else
                afrag[kc] = (half8)(_Float16)0.0f;
        }
    }

#pragma unroll
    for (int h = 0; h < 2; h++) {
        if (h) __syncthreads();
#pragma unroll
        for (int t = 0; t < 8; t++) {
            int idx = tid + t * 256;
            int r = idx >> 4, kb = (idx & 15) * 8;
            *(half8*)&Ws[r][kb] = *(const half8*)(W1T + (size_t)(h * 128 + r) * HDIM + kb);
        }
        __syncthreads();
        f32x4 acc[8] = {};
#pragma unroll
        for (int kc = 0; kc < 4; kc++) {
#pragma unroll
            for (int j = 0; j < 8; j++) {
                half8 bb = *(const half8*)&Ws[j * 16 + l16][kc * 32 + quad * 8];
                acc[j] = __builtin_amdgcn_mfma_f32_16x16x32_f16(afrag[kc], bb, acc[j], 0, 0, 0);
            }
        }
#pragma unroll
        for (int j = 0; j < 8; j++) {
            float bj1 = b1[h * 128 + j * 16 + l16];
#pragma unroll
            for (int r = 0; r < 4; r++) {
                float v = acc[j][r] + bj1;
                v = 0.5f * v * (1.0f + erff(v * 0.70710678118654752f));
                Mid[wave * 16 + quad * 4 + r][h * 128 + j * 16 + l16] = (_Float16)v;
            }
        }
    }
    __syncthreads();

    f32x4 acc2[8] = {};
#pragma unroll
    for (int kc2 = 0; kc2 < 2; kc2++) {
        if (kc2) __syncthreads();
#pragma unroll
        for (int t = 0; t < 8; t++) {
            int idx = tid + t * 256;
            int r = idx >> 4, kb = (idx & 15) * 8;
            *(half8*)&Ws[r][kb] = *(const half8*)(W2T + (size_t)r * FFH + kc2 * 128 + kb);
        }
        __syncthreads();
#pragma unroll
        for (int kc = 0; kc < 4; kc++) {
            half8 am = *(const half8*)&Mid[wave * 16 + l16][kc2 * 128 + kc * 32 + quad * 8];
#pragma unroll
            for (int j = 0; j < 8; j++) {
                half8 bb = *(const half8*)&Ws[j * 16 + l16][kc * 32 + quad * 8];
                acc2[j] = __builtin_amdgcn_mfma_f32_16x16x32_f16(am, bb, acc2[j], 0, 0, 0);
            }
        }
    }

    float gj[8], bj[8], b2j[8];
#pragma unroll
    for (int j = 0; j < 8; j++) {
        int col = j * 16 + l16;
        b2j[j] = b2[col];
        gj[j] = g[col];
        bj[j] = b[col];
    }
    int row0 = mBase + wave * 16 + quad * 4;
    float sum[4] = {}, sq[4] = {};
#pragma unroll
    for (int r = 0; r < 4; r++) {
        int row = row0 + r;
        bool ok = row < M;
        size_t base = (size_t)row * HDIM;
#pragma unroll
        for (int j = 0; j < 8; j++) {
            float v = acc2[j][r] + b2j[j] + (ok ? R[base + j * 16 + l16] : 0.0f);
            acc2[j][r] = v;
            sum[r] += v;
            sq[r] += v * v;
        }
    }
#pragma unroll
    for (int r = 0; r < 4; r++) {
#pragma unroll
        for (int off = 1; off < 16; off <<= 1) {
            sum[r] += __shfl_xor(sum[r], off);
            sq[r] += __shfl_xor(sq[r], off);
        }
    }
#pragma unroll
    for (int r = 0; r < 4; r++) {
        int row = row0 + r;
        if (row >= M) continue;
        size_t base = (size_t)row * HDIM;
        float mu = sum[r] * (1.0f / HDIM);
        float var = sq[r] * (1.0f / HDIM) - mu * mu;
        float invstd = rsqrtf(var + 1e-5f);
#pragma unroll
        for (int j = 0; j < 8; j++) {
            float o = (acc2[j][r] - mu) * invstd * gj[j] + bj[j];
            C32[base + j * 16 + l16] = o;
            if (C16) C16[base + j * 16 + l16] = (_Float16)o;
        }
    }
}

// ---------------------------------------------------------------------------
// GATv2 attention + aggregation, split-edge: 2 waves per dst node, each runs
// a 4-edge-unrolled online softmax on half the edge list; halves merged in
// LDS (flash-merge: rescale by exp(m - m*)). Epilogue by even wave.
// Block = 256 threads = 2 nodes x 2 waves.
// r10: f16 pre-converted weights (vector prologue loads), unroll 2->4 for
// gather MLP + amortized softmax chain, 32-bit saddr addressing.
// ---------------------------------------------------------------------------
__global__ __launch_bounds__(256) void gat_edge_kernel(
    const _Float16* __restrict__ XLR,
    const int* __restrict__ row_ptr, const Edge* __restrict__ csr,
    const _Float16* __restrict__ WEH,   // [1024] f16: w0 | w1
    const _Float16* __restrict__ ATTH,  // [512] f16
    const _Float16* __restrict__ CBH,   // [512] f16 (concat) or null
    const float* __restrict__ cb2,      // [128] f32 (non-concat)
    _Float16* __restrict__ OUT16, float* __restrict__ OUT32,
    const float* __restrict__ R, const float* __restrict__ lng,
    const float* __restrict__ lnb, _Float16* __restrict__ OUT16h,
    int n, int concat) {
    __shared__ float sM[2][64], sL[2][64];
    __shared__ h8 sAcc[2][64];
    int tid = threadIdx.x;
    int wave = tid >> 6, lane = tid & 63;
    int nodeIdx = wave >> 1;       // 0..1
    int half = wave & 1;
    int node = blockIdx.x * 2 + nodeIdx;
    bool active = node < n;
    int c0 = lane * 8;

    h8 w08  = *(const h8*)(WEH + c0);
    h8 w18  = *(const h8*)(WEH + 512 + c0);
    h8 att8 = *(const h8*)(ATTH + c0);
    const _Float16 slope = (_Float16)NEG_SLOPE;

    h8 xr8 = (h8)(_Float16)0.0f;
    h8 acc2 = (h8)(_Float16)0.0f;
    float m = -INFINITY, l = 0.0f;

    if (active) {
        xr8 = *(const h8*)(XLR + (((unsigned)node << 10) + 512 + c0));
        int beg = row_ptr[node], end = row_ptr[node + 1];
        int mid = beg + ((end - beg + 1) >> 1);
        int b0 = half ? mid : beg;
        int e0 = half ? end : mid;
        int j = b0;
        for (; j + 3 < e0; j += 4) {
            Edge eg0 = csr[j], eg1 = csr[j + 1], eg2 = csr[j + 2], eg3 = csr[j + 3];
            const h8 x0 = *(const h8*)(XLR + (((unsigned)eg0.src << 10) + c0));
            const h8 x1 = *(const h8*)(XLR + (((unsigned)eg1.src << 10) + c0));
            const h8 x2 = *(const h8*)(XLR + (((unsigned)eg2.src << 10) + c0));
            const h8 x3 = *(const h8*)(XLR + (((unsigned)eg3.src << 10) + c0));
            h8 v0 = x0 + (xr8 + w08 * eg0.ea0 + w18 * eg0.ea1);
            h8 v1 = x1 + (xr8 + w08 * eg1.ea0 + w18 * eg1.ea1);
            h8 v2 = x2 + (xr8 + w08 * eg2.ea0 + w18 * eg2.ea1);
            h8 v3 = x3 + (xr8 + w08 * eg3.ea0 + w18 * eg3.ea1);
            v0 = __builtin_elementwise_max(v0, v0 * slope);
            v1 = __builtin_elementwise_max(v1, v1 * slope);
            v2 = __builtin_elementwise_max(v2, v2 * slope);
            v3 = __builtin_elementwise_max(v3, v3 * slope);
            float p0 = hsum8(v0 * att8);
            float p1 = hsum8(v1 * att8);
            float p2 = hsum8(v2 * att8);
            float p3 = hsum8(v3 * att8);
#pragma unroll
            for (int off = 1; off < 16; off <<= 1) {
                p0 += __shfl_xor(p0, off);
                p1 += __shfl_xor(p1, off);
                p2 += __shfl_xor(p2, off);
                p3 += __shfl_xor(p3, off);
            }
            float mnew = fmaxf(m, fmaxf(fmaxf(p0, p1), fmaxf(p2, p3)));
            float sc  = __expf(m - mnew);
            float e0f = __expf(p0 - mnew);
            float e1f = __expf(p1 - mnew);
            float e2f = __expf(p2 - mnew);
            float e3f = __expf(p3 - mnew);
            l = l * sc + ((e0f + e1f) + (e2f + e3f));
            acc2 = acc2 * (_Float16)sc
                 + (x0 * (_Float16)e0f + x1 * (_Float16)e1f)
                 + (x2 * (_Float16)e2f + x3 * (_Float16)e3f);
            m = mnew;
        }
        for (; j < e0; j++) {
            Edge eg0 = csr[j];
            const h8 x0 = *(const h8*)(XLR + (((unsigned)eg0.src << 10) + c0));
            h8 v0 = x0 + (xr8 + w08 * eg0.ea0 + w18 * eg0.ea1);
            v0 = __builtin_elementwise_max(v0, v0 * slope);
            float p0 = hsum8(v0 * att8);
            p0 += __shfl_xor(p0, 1);
            p0 += __shfl_xor(p0, 2);
            p0 += __shfl_xor(p0, 4);
            p0 += __shfl_xor(p0, 8);
            float mnew = fmaxf(m, p0);
            float sc = __expf(m - mnew);
            float e0f = __expf(p0 - mnew);
            l = l * sc + e0f;
            acc2 = acc2 * (_Float16)sc + x0 * (_Float16)e0f;
            m = mnew;
        }
    }

    // ---- merge the two halves via LDS ----
    if (half == 1) {
        sM[nodeIdx][lane] = m;
        sL[nodeIdx][lane] = l;
        sAcc[nodeIdx][lane] = acc2;
    }
    __syncthreads();
    if (half != 0 || !active) return;
    {
        float mB = sM[nodeIdx][lane];
        float lB = sL[nodeIdx][lane];
        h8 accB = sAcc[nodeIdx][lane];
        float mS = fmaxf(m, mB);
        float sA = __expf(m - mS);          // m is finite (half0 has >=1 edge)
        float sB = __expf(mB - mS);         // exp(-inf)=0 handles empty half
        l = l * sA + lB * sB;
        acc2 = acc2 * (_Float16)sA + accB * (_Float16)sB;
    }

    float invf = 1.0f / (l + 1e-16f);
    if (concat) {
        h8 cb8 = *(const h8*)(CBH + c0);
        h8 o = acc2 * (_Float16)invf + cb8;
        *(h8*)(OUT16 + (((unsigned)node << 10) + c0)) = o;
    } else {
        float o8[8];
#pragma unroll
        for (int k = 0; k < 8; k++) {
            float a = (float)acc2[k] * invf;
            a += __shfl_xor(a, 16);
            a += __shfl_xor(a, 32);
            o8[k] = a;
        }
        float v8[8];
        float sum = 0.0f, sq = 0.0f;
        if (lane < 16) {
#pragma unroll
            for (int k = 0; k < 8; k++) {
                float v = o8[k] * 0.25f + cb2[c0 + k] + R[(size_t)node * HDIM + c0 + k];
                v8[k] = v;
                sum += v;
                sq += v * v;
            }
        }
#pragma unroll
        for (int off = 1; off < 16; off <<= 1) {
            sum += __shfl_xor(sum, off);
            sq += __shfl_xor(sq, off);
        }
        if (lane < 16) {
            float mu = sum * (1.0f / HDIM);
            float var = sq * (1.0f / HDIM) - mu * mu;
            float invstd = rsqrtf(var + 1e-5f);
#pragma unroll
            for (int k = 0; k < 8; k++) {
                float o = (v8[k] - mu) * invstd * lng[c0 + k] + lnb[c0 + k];
                OUT32[(size_t)node * HDIM + c0 + k] = o;
                OUT16h[(size_t)node * HDIM + c0 + k] = (_Float16)o;
            }
        }
    }
}

// ---------------------------------------------------------------------------
extern "C" void kernel_launch(void* const* d_in, const int* in_sizes, int n_in,
                              void* d_out, int out_size, void* d_ws, size_t ws_size,
                              hipStream_t stream) {
    const float* x        = (const float*)d_in[0];
    const int*   ei       = (const int*)d_in[1];
    const float* eattr    = (const float*)d_in[2];
    const float* emb_w    = (const float*)d_in[3];
    const float* emb_b    = (const float*)d_in[4];
    const float* lin_l    = (const float*)d_in[5];
    const float* lin_r    = (const float*)d_in[6];
    const float* lin_edge = (const float*)d_in[7];
    const float* attw     = (const float*)d_in[8];
    const float* cb01     = (const float*)d_in[9];
    const float* cb2      = (const float*)d_in[10];
    const float* proj_w   = (const float*)d_in[11];
    const float* proj_b   = (const float*)d_in[12];
    const float* n1g      = (const float*)d_in[13];
    const float* n1b      = (const float*)d_in[14];
    const float* n2g      = (const float*)d_in[15];
    const float* n2b      = (const float*)d_in[16];
    const float* fw1      = (const float*)d_in[17];
    const float* fb1      = (const float*)d_in[18];
    const float* fw2      = (const float*)d_in[19];
    const float* fb2      = (const float*)d_in[20];
    float* out = (float*)d_out;

    const int n = in_sizes[0] / IN_DIM;   // 20000
    const int E = in_sizes[2] / 2;        // 320000
    const int EP = E + n;
    const int numMT = (n + 63) / 64;

    size_t off = 0;
    auto alloc = [&](size_t bytes) {
        void* p = (char*)d_ws + off;
        off += (bytes + 255) & ~(size_t)255;
        return p;
    };
    float* deg     = (float*)alloc((size_t)n * 4);
    float* asum    = (float*)alloc((size_t)2 * n * 4);
    int*   row_ptr = (int*)alloc((size_t)(n + 1) * 4);
    int*   cur     = (int*)alloc((size_t)n * 4);
    Edge*  csr     = (Edge*)alloc((size_t)EP * 8);
    float* H0      = (float*)alloc((size_t)n * HDIM * 4);
    float* H1      = (float*)alloc((size_t)n * HDIM * 4);
    _Float16* H0h  = (_Float16*)alloc((size_t)n * HDIM * 2);
    _Float16* H1h  = (_Float16*)alloc((size_t)n * HDIM * 2);
    _Float16* XLR  = (_Float16*)alloc((size_t)n * 1024 * 2);
    _Float16* xh   = (_Float16*)alloc((size_t)n * 64 * 2);
    _Float16* wt_emb  = (_Float16*)alloc((size_t)HDIM * 64 * 2);
    _Float16* wt_llr  = (_Float16*)alloc((size_t)3 * 1024 * HDIM * 2);
    _Float16* wt_proj = (_Float16*)alloc((size_t)2 * HDIM * HH * 2);
    _Float16* wt_f1   = (_Float16*)alloc((size_t)3 * FFH * HDIM * 2);
    _Float16* wt_f2   = (_Float16*)alloc((size_t)3 * HDIM * FFH * 2);
    _Float16* weh     = (_Float16*)alloc((size_t)3 * 1024 * 2);
    _Float16* atth    = (_Float16*)alloc((size_t)3 * 512 * 2);
    _Float16* cbh     = (_Float16*)alloc((size_t)2 * 512 * 2);
    (void)ws_size;

    // ---- input prep ----
    xpad_kernel<<<(n * 64 + 255) / 256, 256, 0, stream>>>(x, xh, n);
    WDescs ds;
    int di = 0;
    ds.d[di++] = {emb_w, wt_emb, IN_DIM, 6, 7};
    for (int i = 0; i < 3; i++) {
        ds.d[di++] = {lin_l + (size_t)i * HDIM * HH, wt_llr + (size_t)i * 1024 * HDIM, HDIM, 7, 9};
        ds.d[di++] = {lin_r + (size_t)i * HDIM * HH, wt_llr + (size_t)i * 1024 * HDIM + (size_t)512 * HDIM, HDIM, 7, 9};
    }
    for (int i = 0; i < 2; i++)
        ds.d[di++] = {proj_w + (size_t)i * HH * HDIM, wt_proj + (size_t)i * HDIM * HH, HH, 9, 7};
    for (int i = 0; i < 3; i++)
        ds.d[di++] = {fw1 + (size_t)i * HDIM * FFH, wt_f1 + (size_t)i * FFH * HDIM, HDIM, 7, 8};
    for (int i = 0; i < 3; i++)
        ds.d[di++] = {fw2 + (size_t)i * FFH * HDIM, wt_f2 + (size_t)i * HDIM * FFH, FFH, 8, 7};
    wconv_kernel<<<dim3(32, 15), 256, 0, stream>>>(ds);
    wcvt_kernel<<<22, 256, 0, stream>>>(lin_edge, attw, cb01, weh, atth, cbh);

    // ---- CSR build ----
    (void)hipMemsetAsync(deg, 0, (size_t)n * 4, stream);
    (void)hipMemsetAsync(asum, 0, (size_t)2 * n * 4, stream);
    deg_kernel<<<(E + 255) / 256, 256, 0, stream>>>(ei, eattr, deg, asum, E);
    scan_kernel<<<1, 1024, 0, stream>>>(deg, row_ptr, cur, n);
    scatter_kernel<<<(EP + 255) / 256, 256, 0, stream>>>(ei, eattr, deg, asum, cur, csr, E, n);

    // ---- Embedding: H0(+H0h) = xh @ wt_emb + emb_b (B-stationary) ----
    gemm_bstat<64, 2><<<dim3(1, numMT), 256, 0, stream>>>(
        xh, 64, wt_emb, emb_b, H0, H0h, n, HDIM, numMT);

    // ---- 3 GATv2 + FFN layers ----
    for (int i = 0; i < 3; i++) {
        int concat = (i < 2);
        // fused lin_l|lin_r: XLR[n][1024] (B-stationary, barrier-free M loop)
        gemm_bstat<128, 1><<<dim3(8, 80), 256, 0, stream>>>(
            H0h, HDIM, wt_llr + (size_t)i * 1024 * HDIM, nullptr,
            nullptr, XLR, n, 1024, numMT);
        // gat: 2 waves/node split-edge; concat -> f16 into XR half;
        // non-concat -> fused mean+bias+res+LN
        gat_edge_kernel<<<(n + 1) / 2, 256, 0, stream>>>(
            XLR, row_ptr, csr,
            weh + (size_t)i * 1024, atth + (size_t)i * 512,
            concat ? (cbh + (size_t)i * 512) : nullptr, cb2,
            XLR + 512, H1,
            H0, n1g + (size_t)i * HDIM, n1b + (size_t)i * HDIM, H1h,
            n, concat);
        if (concat) {
            // H1,H1h = LN(proj(gatout) + pb + H0)
            gemm_ln<<<(n + 63) / 64, 256, 0, stream>>>(
                XLR + 512, 1024, wt_proj + (size_t)i * HDIM * HH,
                proj_b + (size_t)i * HDIM, H0,
                n1g + (size_t)i * HDIM, n1b + (size_t)i * HDIM,
                H1, H1h, n, HH);
        }
        // {out|H0,H0h} = LN(GELU(H1h@W1+b1)@W2 + b2 + H1)
        float* lnout = (i == 2) ? out : H0;
        _Float16* lnout16 = (i == 2) ? nullptr : H0h;
        ffn_fused<<<(n + 63) / 64, 256, 0, stream>>>(
            H1h, wt_f1 + (size_t)i * FFH * HDIM, fb1 + (size_t)i * FFH,
            wt_f2 + (size_t)i * HDIM * FFH, fb2 + (size_t)i * HDIM, H1,
            n2g + (size_t)i * HDIM, n2b + (size_t)i * HDIM,
            lnout, lnout16, n);
    }
}

// Round 2
// 564.592 us; speedup vs baseline: 1.0041x; 1.0041x over previous
//
#include <hip/hip_runtime.h>
#include <math.h>

#define IN_DIM 16
#define HDIM   128
#define HEADS  4
#define HH     512   // HEADS*HDIM
#define FFH    256   // 2*HDIM
#define NEG_SLOPE 0.2f

typedef _Float16 half8 __attribute__((ext_vector_type(8)));
typedef _Float16 h8 __attribute__((ext_vector_type(8)));
typedef _Float16 h4 __attribute__((ext_vector_type(4)));
typedef _Float16 h2 __attribute__((ext_vector_type(2)));
typedef float f32x4 __attribute__((ext_vector_type(4)));
typedef int i32x4 __attribute__((ext_vector_type(4)));

struct __align__(8) Edge { int src; _Float16 ea0, ea1; };

static __device__ inline float hsum8(h8 v) {
    h4 a = __builtin_shufflevector(v, v, 0, 1, 2, 3) +
           __builtin_shufflevector(v, v, 4, 5, 6, 7);
    h2 b = __builtin_shufflevector(a, a, 0, 1) +
           __builtin_shufflevector(a, a, 2, 3);
    return (float)b[0] + (float)b[1];
}

static __device__ inline h8 shfl_xor_h8(h8 v, int off) {
    union { h8 h; i32x4 i; } u;
    u.h = v;
    u.i.x = __shfl_xor(u.i.x, off);
    u.i.y = __shfl_xor(u.i.y, off);
    u.i.z = __shfl_xor(u.i.z, off);
    u.i.w = __shfl_xor(u.i.w, off);
    return u.h;
}

// ---------------------------------------------------------------------------
// x pad: xh[n][64] = f16(x[n][16]) zero-padded
// ---------------------------------------------------------------------------
__global__ void xpad_kernel(const float* __restrict__ x, _Float16* __restrict__ xh, int n) {
    int idx = blockIdx.x * 256 + threadIdx.x;
    if (idx >= n * 64) return;
    int r = idx >> 6, k = idx & 63;
    xh[idx] = (k < IN_DIM) ? (_Float16)x[r * IN_DIM + k] : (_Float16)0.0f;
}

// ---------------------------------------------------------------------------
// Weight convert+transpose+K-pad: W[Ksrc][N] fp32 -> WT[N][Kd] f16 (zero pad)
// ---------------------------------------------------------------------------
struct WDesc { const float* src; _Float16* dst; int Ksrc; int lgKd; int lgN; };
struct WDescs { WDesc d[15]; };
__global__ void wconv_kernel(WDescs ds) {
    WDesc w = ds.d[blockIdx.y];
    int Kd = 1 << w.lgKd;
    int total = 1 << (w.lgKd + w.lgN);
    for (int idx = blockIdx.x * 256 + threadIdx.x; idx < total; idx += gridDim.x * 256) {
        int n2 = idx >> w.lgKd, k = idx & (Kd - 1);
        w.dst[idx] = (k < w.Ksrc) ? (_Float16)w.src[(k << w.lgN) + n2] : (_Float16)0.0f;
    }
}

// ---------------------------------------------------------------------------
// Flat f32 -> f16 convert for GAT attention weights / biases.
// we: lin_edge [3*1024], att: [3*512], cb: conv_bias01 [2*512]
// ---------------------------------------------------------------------------
__global__ void wcvt_kernel(const float* __restrict__ we, const float* __restrict__ att,
                            const float* __restrict__ cb,
                            _Float16* __restrict__ weh, _Float16* __restrict__ atth,
                            _Float16* __restrict__ cbh) {
    int i = blockIdx.x * 256 + threadIdx.x;
    if (i < 3072) weh[i] = (_Float16)we[i];
    else if (i < 4608) atth[i - 3072] = (_Float16)att[i - 3072];
    else if (i < 5632) cbh[i - 4608] = (_Float16)cb[i - 4608];
}

// ---------------------------------------------------------------------------
// Preprocess: degree + edge_attr sums (self-loop fill_value='mean')
// ---------------------------------------------------------------------------
__global__ void deg_kernel(const int* __restrict__ ei, const float* __restrict__ eattr,
                           float* deg, float* asum, int E) {
    int e = blockIdx.x * blockDim.x + threadIdx.x;
    if (e >= E) return;
    int d = ei[E + e];
    atomicAdd(&deg[d], 1.0f);
    atomicAdd(&asum[2 * d], eattr[2 * e]);
    atomicAdd(&asum[2 * d + 1], eattr[2 * e + 1]);
}

__global__ void scan_kernel(const float* __restrict__ deg, int* row_ptr, int* cur, int n) {
    __shared__ int sums[1024];
    int tid = threadIdx.x;
    int per = (n + 1023) / 1024;
    int s0 = tid * per;
    int s1 = s0 + per; if (s1 > n) s1 = n;
    int s = 0;
    for (int i = s0; i < s1; i++) s += (int)deg[i] + 1;
    int mysum = s;
    sums[tid] = s;
    __syncthreads();
    for (int dd = 1; dd < 1024; dd <<= 1) {
        int t = (tid >= dd) ? sums[tid - dd] : 0;
        __syncthreads();
        sums[tid] += t;
        __syncthreads();
    }
    int run = sums[tid] - mysum;   // exclusive prefix
    for (int i = s0; i < s1; i++) {
        row_ptr[i] = run; cur[i] = run;
        run += (int)deg[i] + 1;
    }
    if (tid == 1023) row_ptr[n] = sums[1023];
}

__global__ void scatter_kernel(const int* __restrict__ ei, const float* __restrict__ eattr,
                               const float* __restrict__ deg, const float* __restrict__ asum,
                               int* cur, Edge* csr, int E, int n) {
    int i = blockIdx.x * blockDim.x + threadIdx.x;
    if (i >= E + n) return;
    Edge ed;
    int pos;
    if (i < E) {
        int d = ei[E + i];
        pos = atomicAdd(&cur[d], 1);
        ed.src = ei[i];
        ed.ea0 = (_Float16)eattr[2 * i];
        ed.ea1 = (_Float16)eattr[2 * i + 1];
    } else {
        int nd = i - E;
        float dv = fmaxf(deg[nd], 1.0f);
        pos = atomicAdd(&cur[nd], 1);
        ed.src = nd;
        ed.ea0 = (_Float16)(asum[2 * nd] / dv);
        ed.ea1 = (_Float16)(asum[2 * nd + 1] / dv);
    }
    csr[pos] = ed;
}

// ---------------------------------------------------------------------------
// B-stationary MFMA GEMM for K<=128 (see r9 notes): BT staged once, B-frags
// in registers, barrier-free grid-stride M loop, A direct from global.
// ---------------------------------------------------------------------------
template <int KT, int OUTMODE>
__global__ __launch_bounds__(256) void gemm_bstat(const _Float16* __restrict__ A, int lda,
                                                  const _Float16* __restrict__ BT,
                                                  const float* __restrict__ bias,
                                                  float* __restrict__ C32,
                                                  _Float16* __restrict__ C16,
                                                  int M, int Nstride, int numMT) {
    const int PAD = 8, KC = KT / 32;
    __shared__ _Float16 Bs[128][KT + PAD];
    int tid = threadIdx.x;
    int wave = tid >> 6, lane = tid & 63;
    int quad = lane >> 4, l16 = lane & 15;
    int wrow = (wave >> 1) * 32, wcol = (wave & 1) * 64;
    int n0 = blockIdx.x * 128;

#pragma unroll
    for (int t = 0; t < KT / 16; t++) {
        int idx = tid + t * 256;
        int r = idx / (KT / 8), kb = (idx % (KT / 8)) * 8;
        *(half8*)&Bs[r][kb] = *(const half8*)(BT + (size_t)(n0 + r) * KT + kb);
    }
    __syncthreads();

    half8 bfrag[4][KC];
#pragma unroll
    for (int j = 0; j < 4; j++)
#pragma unroll
        for (int kc = 0; kc < KC; kc++)
            bfrag[j][kc] = *(const half8*)&Bs[wcol + j * 16 + l16][kc * 32 + quad * 8];

    float biasj[4];
#pragma unroll
    for (int j = 0; j < 4; j++)
        biasj[j] = bias ? bias[n0 + wcol + j * 16 + l16] : 0.0f;

    for (int mt = blockIdx.y; mt < numMT; mt += gridDim.y) {
        int rbase = mt * 64 + wrow;
        half8 af[2][KC];
#pragma unroll
        for (int i = 0; i < 2; i++) {
            int row = rbase + i * 16 + l16;
#pragma unroll
            for (int kc = 0; kc < KC; kc++)
                af[i][kc] = (row < M) ? *(const half8*)(A + (size_t)row * lda + kc * 32 + quad * 8)
                                      : (half8)(_Float16)0.0f;
        }
        f32x4 acc[2][4] = {};
#pragma unroll
        for (int kc = 0; kc < KC; kc++)
#pragma unroll
            for (int i = 0; i < 2; i++)
#pragma unroll
                for (int j = 0; j < 4; j++)
                    acc[i][j] = __builtin_amdgcn_mfma_f32_16x16x32_f16(af[i][kc], bfrag[j][kc], acc[i][j], 0, 0, 0);
#pragma unroll
        for (int i = 0; i < 2; i++) {
#pragma unroll
            for (int r = 0; r < 4; r++) {
                int row = rbase + i * 16 + quad * 4 + r;
                if (row >= M) continue;
#pragma unroll
                for (int j = 0; j < 4; j++) {
                    int col = n0 + wcol + j * 16 + l16;
                    float v = acc[i][j][r] + biasj[j];
                    if (OUTMODE == 2)
                        C32[(size_t)row * Nstride + col] = v;
                    C16[(size_t)row * Nstride + col] = (_Float16)v;
                }
            }
        }
    }
}

// ---------------------------------------------------------------------------
// Fused GEMM(+bias) + residual + LayerNorm for N=128, register-resident LN.
// ---------------------------------------------------------------------------
__global__ __launch_bounds__(256) void gemm_ln(const _Float16* __restrict__ A, int lda,
                                               const _Float16* __restrict__ BT,
                                               const float* __restrict__ bias,
                                               const float* __restrict__ R,
                                               const float* __restrict__ g,
                                               const float* __restrict__ b,
                                               float* __restrict__ C32,
                                               _Float16* __restrict__ C16,
                                               int M, int K) {
    const int BK = 64, PAD = 8;
    __shared__ _Float16 As[64][BK + PAD];
    __shared__ _Float16 Bs[128][BK + PAD];
    int tid = threadIdx.x;
    int wave = tid >> 6, lane = tid & 63;
    int quad = lane >> 4, l16 = lane & 15;
    int mBase = blockIdx.x * 64;

    f32x4 acc[8] = {};

    for (int k0 = 0; k0 < K; k0 += BK) {
#pragma unroll
        for (int t = 0; t < 2; t++) {
            int idx = tid + t * 256;
            int r = idx >> 3, kb = (idx & 7) * 8;
            half8 hv = {};
            int grow = mBase + r;
            if (grow < M) hv = *(const half8*)(A + (size_t)grow * lda + k0 + kb);
            *(half8*)&As[r][kb] = hv;
        }
#pragma unroll
        for (int t = 0; t < 4; t++) {
            int idx = tid + t * 256;
            int r = idx >> 3, kb = (idx & 7) * 8;
            *(half8*)&Bs[r][kb] = *(const half8*)(BT + (size_t)r * K + k0 + kb);
        }
        __syncthreads();
#pragma unroll
        for (int kc = 0; kc < 2; kc++) {
            half8 a = *(const half8*)&As[wave * 16 + l16][kc * 32 + quad * 8];
#pragma unroll
            for (int j = 0; j < 8; j++) {
                half8 bb = *(const half8*)&Bs[j * 16 + l16][kc * 32 + quad * 8];
                acc[j] = __builtin_amdgcn_mfma_f32_16x16x32_f16(a, bb, acc[j], 0, 0, 0);
            }
        }
        __syncthreads();
    }

    float gj[8], bj[8], biasj[8];
#pragma unroll
    for (int j = 0; j < 8; j++) {
        int col = j * 16 + l16;
        biasj[j] = bias[col];
        gj[j] = g[col];
        bj[j] = b[col];
    }
    int row0 = mBase + wave * 16 + quad * 4;
    float sum[4] = {}, sq[4] = {};
#pragma unroll
    for (int r = 0; r < 4; r++) {
        int row = row0 + r;
        bool ok = row < M;
        size_t base = (size_t)row * HDIM;
#pragma unroll
        for (int j = 0; j < 8; j++) {
            float v = acc[j][r] + biasj[j] + (ok ? R[base + j * 16 + l16] : 0.0f);
            acc[j][r] = v;
            sum[r] += v;
            sq[r] += v * v;
        }
    }
#pragma unroll
    for (int r = 0; r < 4; r++) {
#pragma unroll
        for (int off = 1; off < 16; off <<= 1) {
            sum[r] += __shfl_xor(sum[r], off);
            sq[r] += __shfl_xor(sq[r], off);
        }
    }
#pragma unroll
    for (int r = 0; r < 4; r++) {
        int row = row0 + r;
        if (row >= M) continue;
        size_t base = (size_t)row * HDIM;
        float mu = sum[r] * (1.0f / HDIM);
        float var = sq[r] * (1.0f / HDIM) - mu * mu;
        float invstd = rsqrtf(var + 1e-5f);
#pragma unroll
        for (int j = 0; j < 8; j++) {
            float o = (acc[j][r] - mu) * invstd * gj[j] + bj[j];
            C32[base + j * 16 + l16] = o;
            if (C16) C16[base + j * 16 + l16] = (_Float16)o;
        }
    }
}

// ---------------------------------------------------------------------------
// Fused FFN: C = LN(GELU(A@W1T + b1)@W2T + b2 + R) * g + b.
// ---------------------------------------------------------------------------
__global__ __launch_bounds__(256) void ffn_fused(const _Float16* __restrict__ A,
                                                 const _Float16* __restrict__ W1T,
                                                 const float* __restrict__ b1,
                                                 const _Float16* __restrict__ W2T,
                                                 const float* __restrict__ b2,
                                                 const float* __restrict__ R,
                                                 const float* __restrict__ g,
                                                 const float* __restrict__ b,
                                                 float* __restrict__ C32,
                                                 _Float16* __restrict__ C16,
                                                 int M) {
    __shared__ _Float16 Ws[128][128 + 8];
    __shared__ _Float16 Mid[64][256 + 8];
    int tid = threadIdx.x;
    int wave = tid >> 6, lane = tid & 63;
    int quad = lane >> 4, l16 = lane & 15;
    int mBase = blockIdx.x * 64;

    half8 afrag[4];
    {
        int row = mBase + wave * 16 + l16;
#pragma unroll
        for (int kc = 0; kc < 4; kc++) {
            if (row < M)
                afrag[kc] = *(const half8*)(A + (size_t)row * HDIM + kc * 32 + quad * 8);
            else
                afrag[kc] = (half8)(_Float16)0.0f;
        }
    }

#pragma unroll
    for (int h = 0; h < 2; h++) {
        if (h) __syncthreads();
#pragma unroll
        for (int t = 0; t < 8; t++) {
            int idx = tid + t * 256;
            int r = idx >> 4, kb = (idx & 15) * 8;
            *(half8*)&Ws[r][kb] = *(const half8*)(W1T + (size_t)(h * 128 + r) * HDIM + kb);
        }
        __syncthreads();
        f32x4 acc[8] = {};
#pragma unroll
        for (int kc = 0; kc < 4; kc++) {
#pragma unroll
            for (int j = 0; j < 8; j++) {
                half8 bb = *(const half8*)&Ws[j * 16 + l16][kc * 32 + quad * 8];
                acc[j] = __builtin_amdgcn_mfma_f32_16x16x32_f16(afrag[kc], bb, acc[j], 0, 0, 0);
            }
        }
#pragma unroll
        for (int j = 0; j < 8; j++) {
            float bj1 = b1[h * 128 + j * 16 + l16];
#pragma unroll
            for (int r = 0; r < 4; r++) {
                float v = acc[j][r] + bj1;
                v = 0.5f * v * (1.0f + erff(v * 0.70710678118654752f));
                Mid[wave * 16 + quad * 4 + r][h * 128 + j * 16 + l16] = (_Float16)v;
            }
        }
    }
    __syncthreads();

    f32x4 acc2[8] = {};
#pragma unroll
    for (int kc2 = 0; kc2 < 2; kc2++) {
        if (kc2) __syncthreads();
#pragma unroll
        for (int t = 0; t < 8; t++) {
            int idx = tid + t * 256;
            int r = idx >> 4, kb = (idx & 15) * 8;
            *(half8*)&Ws[r][kb] = *(const half8*)(W2T + (size_t)r * FFH + kc2 * 128 + kb);
        }
        __syncthreads();
#pragma unroll
        for (int kc = 0; kc < 4; kc++) {
            half8 am = *(const half8*)&Mid[wave * 16 + l16][kc2 * 128 + kc * 32 + quad * 8];
#pragma unroll
            for (int j = 0; j < 8; j++) {
                half8 bb = *(const half8*)&Ws[j * 16 + l16][kc * 32 + quad * 8];
                acc2[j] = __builtin_amdgcn_mfma_f32_16x16x32_f16(am, bb, acc2[j], 0, 0, 0);
            }
        }
    }

    float gj[8], bj[8], b2j[8];
#pragma unroll
    for (int j = 0; j < 8; j++) {
        int col = j * 16 + l16;
        b2j[j] = b2[col];
        gj[j] = g[col];
        bj[j] = b[col];
    }
    int row0 = mBase + wave * 16 + quad * 4;
    float sum[4] = {}, sq[4] = {};
#pragma unroll
    for (int r = 0; r < 4; r++) {
        int row = row0 + r;
        bool ok = row < M;
        size_t base = (size_t)row * HDIM;
#pragma unroll
        for (int j = 0; j < 8; j++) {
            float v = acc2[j][r] + b2j[j] + (ok ? R[base + j * 16 + l16] : 0.0f);
            acc2[j][r] = v;
            sum[r] += v;
            sq[r] += v * v;
        }
    }
#pragma unroll
    for (int r = 0; r < 4; r++) {
#pragma unroll
        for (int off = 1; off < 16; off <<= 1) {
            sum[r] += __shfl_xor(sum[r], off);
            sq[r] += __shfl_xor(sq[r], off);
        }
    }
#pragma unroll
    for (int r = 0; r < 4; r++) {
        int row = row0 + r;
        if (row >= M) continue;
        size_t base = (size_t)row * HDIM;
        float mu = sum[r] * (1.0f / HDIM);
        float var = sq[r] * (1.0f / HDIM) - mu * mu;
        float invstd = rsqrtf(var + 1e-5f);
#pragma unroll
        for (int j = 0; j < 8; j++) {
            float o = (acc2[j][r] - mu) * invstd * gj[j] + bj[j];
            C32[base + j * 16 + l16] = o;
            if (C16) C16[base + j * 16 + l16] = (_Float16)o;
        }
    }
}

// ---------------------------------------------------------------------------
// GATv2 attention + aggregation, r11 layout: 1 wave per node, 2 edge-groups
// of 32 lanes each (lane covers 16 of 512 dims; head = sub>>3). Per group,
// 2-edge-unrolled online softmax. Score reduce = 3 shfl steps over 8 lanes,
// serving 2 edges at once; exp/fmax chains are per-lane (2 edges x 4 heads
// per v_exp). Groups flash-merged in-wave via shfl_xor(32). No LDS, no
// barriers. Sentinel m=-1e30 (not -inf) keeps empty-group merges NaN-free.
// Block = 256 threads = 4 nodes.
// ---------------------------------------------------------------------------
__global__ __launch_bounds__(256) void gat_edge_kernel(
    const _Float16* __restrict__ XLR,
    const int* __restrict__ row_ptr, const Edge* __restrict__ csr,
    const _Float16* __restrict__ WEH,   // [1024] f16: w0 | w1
    const _Float16* __restrict__ ATTH,  // [512] f16
    const _Float16* __restrict__ CBH,   // [512] f16 (concat) or null
    const float* __restrict__ cb2,      // [128] f32 (non-concat)
    _Float16* __restrict__ OUT16, float* __restrict__ OUT32,
    const float* __restrict__ R, const float* __restrict__ lng,
    const float* __restrict__ lnb, _Float16* __restrict__ OUT16h,
    int n, int concat) {
    int tid = threadIdx.x;
    int wave = tid >> 6, lane = tid & 63;
    int g = lane >> 5;        // edge group 0/1
    int sub = lane & 31;      // lane within group; covers dims [sub*16, sub*16+16)
    int node = blockIdx.x * 4 + wave;
    if (node >= n) return;
    int c0 = sub * 16;

    h8 w0[2], w1[2], att[2], xr[2], acc[2];
#pragma unroll
    for (int k = 0; k < 2; k++) {
        w0[k]  = *(const h8*)(WEH + c0 + k * 8);
        w1[k]  = *(const h8*)(WEH + 512 + c0 + k * 8);
        att[k] = *(const h8*)(ATTH + c0 + k * 8);
        acc[k] = (h8)(_Float16)0.0f;
    }
    const _Float16 slope = (_Float16)NEG_SLOPE;

    {
        unsigned nb = ((unsigned)node << 10) + 512u + (unsigned)c0;
        xr[0] = *(const h8*)(XLR + nb);
        xr[1] = *(const h8*)(XLR + nb + 8);
    }

    float m = -1e30f, l = 0.0f;
    int beg = row_ptr[node], end = row_ptr[node + 1];
    int e = beg + g;   // group g: edges beg+g, beg+g+2, ...

    // unroll-2: process e and e+2 per iteration
    for (; e + 2 < end; e += 4) {
        Edge eg0 = csr[e], eg1 = csr[e + 2];
        unsigned r0 = ((unsigned)eg0.src << 10) + (unsigned)c0;
        unsigned r1 = ((unsigned)eg1.src << 10) + (unsigned)c0;
        h8 x0a = *(const h8*)(XLR + r0);
        h8 x0b = *(const h8*)(XLR + r0 + 8);
        h8 x1a = *(const h8*)(XLR + r1);
        h8 x1b = *(const h8*)(XLR + r1 + 8);

        h8 v;
        h8 p80, p81;
        v = x0a + (xr[0] + w0[0] * eg0.ea0 + w1[0] * eg0.ea1);
        v = __builtin_elementwise_max(v, v * slope);
        p80 = v * att[0];
        v = x0b + (xr[1] + w0[1] * eg0.ea0 + w1[1] * eg0.ea1);
        v = __builtin_elementwise_max(v, v * slope);
        p80 += v * att[1];
        v = x1a + (xr[0] + w0[0] * eg1.ea0 + w1[0] * eg1.ea1);
        v = __builtin_elementwise_max(v, v * slope);
        p81 = v * att[0];
        v = x1b + (xr[1] + w0[1] * eg1.ea0 + w1[1] * eg1.ea1);
        v = __builtin_elementwise_max(v, v * slope);
        p81 += v * att[1];

        float p0 = hsum8(p80);
        float p1 = hsum8(p81);
        p0 += __shfl_xor(p0, 1); p1 += __shfl_xor(p1, 1);
        p0 += __shfl_xor(p0, 2); p1 += __shfl_xor(p1, 2);
        p0 += __shfl_xor(p0, 4); p1 += __shfl_xor(p1, 4);
        // p0/p1 uniform per 8-lane head-group = this head's scores

        float mnew = fmaxf(m, fmaxf(p0, p1));
        float sc  = __expf(m - mnew);
        float e0f = __expf(p0 - mnew);
        float e1f = __expf(p1 - mnew);
        l = l * sc + e0f + e1f;
        _Float16 hs = (_Float16)sc, h0 = (_Float16)e0f, h1 = (_Float16)e1f;
        acc[0] = acc[0] * hs + x0a * h0 + x1a * h1;
        acc[1] = acc[1] * hs + x0b * h0 + x1b * h1;
        m = mnew;
    }
    // tail: at most one edge per group
    for (; e < end; e += 2) {
        Edge eg0 = csr[e];
        unsigned r0 = ((unsigned)eg0.src << 10) + (unsigned)c0;
        h8 x0a = *(const h8*)(XLR + r0);
        h8 x0b = *(const h8*)(XLR + r0 + 8);
        h8 v;
        h8 p80;
        v = x0a + (xr[0] + w0[0] * eg0.ea0 + w1[0] * eg0.ea1);
        v = __builtin_elementwise_max(v, v * slope);
        p80 = v * att[0];
        v = x0b + (xr[1] + w0[1] * eg0.ea0 + w1[1] * eg0.ea1);
        v = __builtin_elementwise_max(v, v * slope);
        p80 += v * att[1];
        float p0 = hsum8(p80);
        p0 += __shfl_xor(p0, 1);
        p0 += __shfl_xor(p0, 2);
        p0 += __shfl_xor(p0, 4);
        float mnew = fmaxf(m, p0);
        float sc  = __expf(m - mnew);
        float e0f = __expf(p0 - mnew);
        l = l * sc + e0f;
        _Float16 hs = (_Float16)sc, h0 = (_Float16)e0f;
        acc[0] = acc[0] * hs + x0a * h0;
        acc[1] = acc[1] * hs + x0b * h0;
        m = mnew;
    }

    // ---- merge the two groups (flash-merge, in-wave) ----
    {
        float m2 = __shfl_xor(m, 32);
        float l2 = __shfl_xor(l, 32);
        h8 a20 = shfl_xor_h8(acc[0], 32);
        h8 a21 = shfl_xor_h8(acc[1], 32);
        float mS = fmaxf(m, m2);
        float sA = __expf(m - mS);
        float sB = __expf(m2 - mS);
        l = l * sA + l2 * sB;
        _Float16 hA = (_Float16)sA, hB = (_Float16)sB;
        acc[0] = acc[0] * hA + a20 * hB;
        acc[1] = acc[1] * hA + a21 * hB;
    }

    float invf = 1.0f / (l + 1e-16f);
    if (concat) {
        _Float16 hi = (_Float16)invf;
        h8 o0 = acc[0] * hi + *(const h8*)(CBH + c0);
        h8 o1 = acc[1] * hi + *(const h8*)(CBH + c0 + 8);
        if (g == 0) {
            unsigned ob = ((unsigned)node << 10) + (unsigned)c0;
            *(h8*)(OUT16 + ob) = o0;
            *(h8*)(OUT16 + ob + 8) = o1;
        }
    } else {
        // per-head normalize, then sum heads (xor 8,16 flips head bits of sub)
        _Float16 hi = (_Float16)invf;
        h8 t0 = acc[0] * hi;
        h8 t1 = acc[1] * hi;
        t0 = t0 + shfl_xor_h8(t0, 8);
        t1 = t1 + shfl_xor_h8(t1, 8);
        t0 = t0 + shfl_xor_h8(t0, 16);
        t1 = t1 + shfl_xor_h8(t1, 16);
        // lanes 0-7 (g==0, head0) now hold head-sums for dims (sub*16 .. +16);
        // together they cover all 128 output dims.
        if (g == 0 && sub < 8) {
            int d0 = sub * 16;
            const float* Rp = R + (size_t)node * HDIM + d0;
            const float* cp = cb2 + d0;
            float v[16];
            float sum = 0.0f, sq = 0.0f;
#pragma unroll
            for (int q = 0; q < 4; q++) {
                f32x4 rv = *(const f32x4*)(Rp + q * 4);
                f32x4 cv = *(const f32x4*)(cp + q * 4);
#pragma unroll
                for (int t = 0; t < 4; t++) {
                    int k2 = q * 4 + t;
                    float base = (k2 < 8) ? (float)t0[k2 & 7] : (float)t1[k2 & 7];
                    float vv = base * 0.25f + cv[t] + rv[t];
                    v[k2] = vv;
                    sum += vv;
                    sq += vv * vv;
                }
            }
            sum += __shfl_xor(sum, 1); sq += __shfl_xor(sq, 1);
            sum += __shfl_xor(sum, 2); sq += __shfl_xor(sq, 2);
            sum += __shfl_xor(sum, 4); sq += __shfl_xor(sq, 4);
            float mu = sum * (1.0f / HDIM);
            float var = sq * (1.0f / HDIM) - mu * mu;
            float invstd = rsqrtf(var + 1e-5f);
            float* op = OUT32 + (size_t)node * HDIM + d0;
            _Float16* oh = OUT16h + (size_t)node * HDIM + d0;
            _Float16 o16[16];
#pragma unroll
            for (int q = 0; q < 4; q++) {
                f32x4 gv = *(const f32x4*)(lng + d0 + q * 4);
                f32x4 bv = *(const f32x4*)(lnb + d0 + q * 4);
                f32x4 ov;
#pragma unroll
                for (int t = 0; t < 4; t++) {
                    float o = (v[q * 4 + t] - mu) * invstd * gv[t] + bv[t];
                    ov[t] = o;
                    o16[q * 4 + t] = (_Float16)o;
                }
                *(f32x4*)(op + q * 4) = ov;
            }
            *(h8*)(oh) = *(h8*)&o16[0];
            *(h8*)(oh + 8) = *(h8*)&o16[8];
        }
    }
}

// ---------------------------------------------------------------------------
extern "C" void kernel_launch(void* const* d_in, const int* in_sizes, int n_in,
                              void* d_out, int out_size, void* d_ws, size_t ws_size,
                              hipStream_t stream) {
    const float* x        = (const float*)d_in[0];
    const int*   ei       = (const int*)d_in[1];
    const float* eattr    = (const float*)d_in[2];
    const float* emb_w    = (const float*)d_in[3];
    const float* emb_b    = (const float*)d_in[4];
    const float* lin_l    = (const float*)d_in[5];
    const float* lin_r    = (const float*)d_in[6];
    const float* lin_edge = (const float*)d_in[7];
    const float* attw     = (const float*)d_in[8];
    const float* cb01     = (const float*)d_in[9];
    const float* cb2      = (const float*)d_in[10];
    const float* proj_w   = (const float*)d_in[11];
    const float* proj_b   = (const float*)d_in[12];
    const float* n1g      = (const float*)d_in[13];
    const float* n1b      = (const float*)d_in[14];
    const float* n2g      = (const float*)d_in[15];
    const float* n2b      = (const float*)d_in[16];
    const float* fw1      = (const float*)d_in[17];
    const float* fb1      = (const float*)d_in[18];
    const float* fw2      = (const float*)d_in[19];
    const float* fb2      = (const float*)d_in[20];
    float* out = (float*)d_out;

    const int n = in_sizes[0] / IN_DIM;   // 20000
    const int E = in_sizes[2] / 2;        // 320000
    const int EP = E + n;
    const int numMT = (n + 63) / 64;

    size_t off = 0;
    auto alloc = [&](size_t bytes) {
        void* p = (char*)d_ws + off;
        off += (bytes + 255) & ~(size_t)255;
        return p;
    };
    float* deg     = (float*)alloc((size_t)n * 4);
    float* asum    = (float*)alloc((size_t)2 * n * 4);
    int*   row_ptr = (int*)alloc((size_t)(n + 1) * 4);
    int*   cur     = (int*)alloc((size_t)n * 4);
    Edge*  csr     = (Edge*)alloc((size_t)EP * 8);
    float* H0      = (float*)alloc((size_t)n * HDIM * 4);
    float* H1      = (float*)alloc((size_t)n * HDIM * 4);
    _Float16* H0h  = (_Float16*)alloc((size_t)n * HDIM * 2);
    _Float16* H1h  = (_Float16*)alloc((size_t)n * HDIM * 2);
    _Float16* XLR  = (_Float16*)alloc((size_t)n * 1024 * 2);
    _Float16* xh   = (_Float16*)alloc((size_t)n * 64 * 2);
    _Float16* wt_emb  = (_Float16*)alloc((size_t)HDIM * 64 * 2);
    _Float16* wt_llr  = (_Float16*)alloc((size_t)3 * 1024 * HDIM * 2);
    _Float16* wt_proj = (_Float16*)alloc((size_t)2 * HDIM * HH * 2);
    _Float16* wt_f1   = (_Float16*)alloc((size_t)3 * FFH * HDIM * 2);
    _Float16* wt_f2   = (_Float16*)alloc((size_t)3 * HDIM * FFH * 2);
    _Float16* weh     = (_Float16*)alloc((size_t)3 * 1024 * 2);
    _Float16* atth    = (_Float16*)alloc((size_t)3 * 512 * 2);
    _Float16* cbh     = (_Float16*)alloc((size_t)2 * 512 * 2);
    (void)ws_size;

    // ---- input prep ----
    xpad_kernel<<<(n * 64 + 255) / 256, 256, 0, stream>>>(x, xh, n);
    WDescs ds;
    int di = 0;
    ds.d[di++] = {emb_w, wt_emb, IN_DIM, 6, 7};
    for (int i = 0; i < 3; i++) {
        ds.d[di++] = {lin_l + (size_t)i * HDIM * HH, wt_llr + (size_t)i * 1024 * HDIM, HDIM, 7, 9};
        ds.d[di++] = {lin_r + (size_t)i * HDIM * HH, wt_llr + (size_t)i * 1024 * HDIM + (size_t)512 * HDIM, HDIM, 7, 9};
    }
    for (int i = 0; i < 2; i++)
        ds.d[di++] = {proj_w + (size_t)i * HH * HDIM, wt_proj + (size_t)i * HDIM * HH, HH, 9, 7};
    for (int i = 0; i < 3; i++)
        ds.d[di++] = {fw1 + (size_t)i * HDIM * FFH, wt_f1 + (size_t)i * FFH * HDIM, HDIM, 7, 8};
    for (int i = 0; i < 3; i++)
        ds.d[di++] = {fw2 + (size_t)i * FFH * HDIM, wt_f2 + (size_t)i * HDIM * FFH, FFH, 8, 7};
    wconv_kernel<<<dim3(32, 15), 256, 0, stream>>>(ds);
    wcvt_kernel<<<22, 256, 0, stream>>>(lin_edge, attw, cb01, weh, atth, cbh);

    // ---- CSR build ----
    (void)hipMemsetAsync(deg, 0, (size_t)n * 4, stream);
    (void)hipMemsetAsync(asum, 0, (size_t)2 * n * 4, stream);
    deg_kernel<<<(E + 255) / 256, 256, 0, stream>>>(ei, eattr, deg, asum, E);
    scan_kernel<<<1, 1024, 0, stream>>>(deg, row_ptr, cur, n);
    scatter_kernel<<<(EP + 255) / 256, 256, 0, stream>>>(ei, eattr, deg, asum, cur, csr, E, n);

    // ---- Embedding: H0(+H0h) = xh @ wt_emb + emb_b (B-stationary) ----
    gemm_bstat<64, 2><<<dim3(1, numMT), 256, 0, stream>>>(
        xh, 64, wt_emb, emb_b, H0, H0h, n, HDIM, numMT);

    // ---- 3 GATv2 + FFN layers ----
    for (int i = 0; i < 3; i++) {
        int concat = (i < 2);
        // fused lin_l|lin_r: XLR[n][1024] (B-stationary, barrier-free M loop)
        gemm_bstat<128, 1><<<dim3(8, 80), 256, 0, stream>>>(
            H0h, HDIM, wt_llr + (size_t)i * 1024 * HDIM, nullptr,
            nullptr, XLR, n, 1024, numMT);
        // gat: 1 wave/node, 2 edge-groups x 32 lanes; concat -> f16 into XR
        // half; non-concat -> fused mean+bias+res+LN
        gat_edge_kernel<<<(n + 3) / 4, 256, 0, stream>>>(
            XLR, row_ptr, csr,
            weh + (size_t)i * 1024, atth + (size_t)i * 512,
            concat ? (cbh + (size_t)i * 512) : nullptr, cb2,
            XLR + 512, H1,
            H0, n1g + (size_t)i * HDIM, n1b + (size_t)i * HDIM, H1h,
            n, concat);
        if (concat) {
            // H1,H1h = LN(proj(gatout) + pb + H0)
            gemm_ln<<<(n + 63) / 64, 256, 0, stream>>>(
                XLR + 512, 1024, wt_proj + (size_t)i * HDIM * HH,
                proj_b + (size_t)i * HDIM, H0,
                n1g + (size_t)i * HDIM, n1b + (size_t)i * HDIM,
                H1, H1h, n, HH);
        }
        // {out|H0,H0h} = LN(GELU(H1h@W1+b1)@W2 + b2 + H1)
        float* lnout = (i == 2) ? out : H0;
        _Float16* lnout16 = (i == 2) ? nullptr : H0h;
        ffn_fused<<<(n + 63) / 64, 256, 0, stream>>>(
            H1h, wt_f1 + (size_t)i * FFH * HDIM, fb1 + (size_t)i * FFH,
            wt_f2 + (size_t)i * HDIM * FFH, fb2 + (size_t)i * HDIM, H1,
            n2g + (size_t)i * HDIM, n2b + (size_t)i * HDIM,
            lnout, lnout16, n);
    }
}